// Round 1
// baseline (864.094 us; speedup 1.0000x reference)
//
#include <hip/hip_runtime.h>
#include <math.h>

typedef __attribute__((ext_vector_type(8))) __bf16 bf16x8;
typedef __attribute__((ext_vector_type(4))) float f32x4;
typedef __attribute__((ext_vector_type(2))) float f32x2;

#define DEV __device__ __forceinline__

DEV unsigned short f2bf(float f) {
    unsigned int u = __builtin_bit_cast(unsigned int, f);
    u += 0x7FFFu + ((u >> 16) & 1u);
    return (unsigned short)(u >> 16);
}
DEV unsigned int pack2(float a, float b) {
    return (unsigned int)f2bf(a) | ((unsigned int)f2bf(b) << 16);
}
DEV float gelu_exact(float v) {
    return 0.5f * v * (1.0f + erff(v * 0.70710678118654752f));
}

// ---------------------------------------------------------------------------
// small prep kernels
// ---------------------------------------------------------------------------
__global__ void cast_bf16_kernel(const float* __restrict__ src,
                                 unsigned short* __restrict__ dst, int n) {
    int i = blockIdx.x * 256 + threadIdx.x;
    if (i < n) dst[i] = f2bf(src[i]);
}

// FW1 (2048 x 514) -> bf16 padded to (2048 x 544), zeros in pad
__global__ void cast_fw1_kernel(const float* __restrict__ src,
                                unsigned short* __restrict__ dst) {
    int i = blockIdx.x * 256 + threadIdx.x;
    if (i < 2048 * 544) {
        int row = i / 544, k = i % 544;
        dst[i] = (k < 514) ? f2bf(src[row * 514 + k]) : (unsigned short)0;
    }
}

// per-batch modulation: gb[b][0..255]=gamma, gb[b][256..511]=beta
__global__ void gb_kernel(const float* __restrict__ x,
                          const float* __restrict__ LW1, const float* __restrict__ Lb1,
                          const float* __restrict__ LW2, const float* __restrict__ Lb2,
                          float* __restrict__ gb) {
    __shared__ float t[512];
    int b = blockIdx.x, tid = threadIdx.x;
    float s0 = x[((size_t)b * 256 + 128) * 514 + 512];
    float s1 = x[((size_t)b * 256 + 128) * 514 + 513];
    for (int j = tid; j < 512; j += 256)
        t[j] = gelu_exact(LW1[j * 2] * s0 + LW1[j * 2 + 1] * s1 + Lb1[j]);
    __syncthreads();
    for (int i = tid; i < 512; i += 256) {
        float a = Lb2[i];
        const float* wr = LW2 + (size_t)i * 512;
        for (int j = 0; j < 512; ++j) a += wr[j] * t[j];
        gb[(size_t)b * 512 + i] = a;
    }
}

// sc passthrough columns 512,513 of output
__global__ void sc_copy_kernel(const float* __restrict__ x, float* __restrict__ out) {
    size_t idx = (size_t)blockIdx.x * 256 + threadIdx.x;  // token index b*256+p
    size_t off = idx * 514 + 512;
    *(f32x2*)(out + off) = *(const f32x2*)(x + off);
}

// ---------------------------------------------------------------------------
// mixer: one workgroup per (b,h). Chain of three 64x256 @ 256x256 GEMMs.
// XT[c][p] (bf16) -> S = (XT@Ws^T+bs)*g+be -> T=gelu(S@HW1^T+Hb1) (into XT)
// -> out = T@HW2^T + Hb2 + residual, written transposed to d_out.
// ---------------------------------------------------------------------------
#define MPAD 264  // 264*2B = 528B row stride: 16B aligned, dw%32==4 (good banking)

__global__ __launch_bounds__(256, 2) void mixer_kernel(
    const float* __restrict__ x, const float* __restrict__ bs,
    const float* __restrict__ Hb1, const float* __restrict__ Hb2,
    const unsigned short* __restrict__ Wsb,
    const unsigned short* __restrict__ HW1b,
    const unsigned short* __restrict__ HW2b,
    const float* __restrict__ gb,
    float* __restrict__ out) {
    __shared__ unsigned short XT[64 * MPAD];
    __shared__ unsigned short S[64 * MPAD];

    const int bid = blockIdx.x;
    const int b = bid >> 3;
    const int h = bid & 7;
    const int tid = threadIdx.x;
    const int lane = tid & 63;
    const int w = tid >> 6;
    const int l15 = lane & 15;
    const int l4 = lane >> 4;

    // ---- stage x^T into LDS as bf16: XT[c][p], c=0..63 (channel), p=0..255 ----
    {
        const int c = lane;  // 0..63
        const float* xp = x + ((size_t)b * 256) * 514 + (size_t)h * 64 + c;
        for (int i = 0; i < 32; ++i) {
            int p = (i * 4 + w) * 2;
            float v0 = xp[(size_t)p * 514];
            float v1 = xp[(size_t)(p + 1) * 514];
            *(unsigned int*)&XT[c * MPAD + p] = pack2(v0, v1);
        }
    }
    __syncthreads();

    f32x4 acc[4][4];

    // ---- stage 1: S[c][o] = (XT @ Ws^T + bs)*gamma + beta ----
    #pragma unroll
    for (int mt = 0; mt < 4; ++mt)
        #pragma unroll
        for (int nt = 0; nt < 4; ++nt) acc[mt][nt] = 0.f;
    for (int kc = 0; kc < 8; ++kc) {
        bf16x8 bfr[4];
        #pragma unroll
        for (int nt = 0; nt < 4; ++nt) {
            int o = w * 64 + nt * 16 + l15;
            bfr[nt] = *(const bf16x8*)(Wsb + (size_t)o * 256 + kc * 32 + l4 * 8);
        }
        #pragma unroll
        for (int mt = 0; mt < 4; ++mt) {
            bf16x8 afr = *(const bf16x8*)&XT[(mt * 16 + l15) * MPAD + kc * 32 + l4 * 8];
            #pragma unroll
            for (int nt = 0; nt < 4; ++nt)
                acc[mt][nt] = __builtin_amdgcn_mfma_f32_16x16x32_bf16(afr, bfr[nt], acc[mt][nt], 0, 0, 0);
        }
    }
    #pragma unroll
    for (int nt = 0; nt < 4; ++nt) {
        int o = w * 64 + nt * 16 + l15;
        float bsv = bs[o];
        float g = gb[(size_t)b * 512 + o];
        float be = gb[(size_t)b * 512 + 256 + o];
        #pragma unroll
        for (int mt = 0; mt < 4; ++mt)
            #pragma unroll
            for (int r = 0; r < 4; ++r) {
                int c = mt * 16 + l4 * 4 + r;
                S[c * MPAD + o] = f2bf((acc[mt][nt][r] + bsv) * g + be);
            }
    }
    __syncthreads();

    // ---- stage 2: T[c][kk] = gelu(S @ HW1[h]^T + Hb1[h])  (write into XT) ----
    const unsigned short* W2p = HW1b + (size_t)h * 65536;
    #pragma unroll
    for (int mt = 0; mt < 4; ++mt)
        #pragma unroll
        for (int nt = 0; nt < 4; ++nt) acc[mt][nt] = 0.f;
    for (int kc = 0; kc < 8; ++kc) {
        bf16x8 bfr[4];
        #pragma unroll
        for (int nt = 0; nt < 4; ++nt) {
            int kk = w * 64 + nt * 16 + l15;
            bfr[nt] = *(const bf16x8*)(W2p + (size_t)kk * 256 + kc * 32 + l4 * 8);
        }
        #pragma unroll
        for (int mt = 0; mt < 4; ++mt) {
            bf16x8 afr = *(const bf16x8*)&S[(mt * 16 + l15) * MPAD + kc * 32 + l4 * 8];
            #pragma unroll
            for (int nt = 0; nt < 4; ++nt)
                acc[mt][nt] = __builtin_amdgcn_mfma_f32_16x16x32_bf16(afr, bfr[nt], acc[mt][nt], 0, 0, 0);
        }
    }
    #pragma unroll
    for (int nt = 0; nt < 4; ++nt) {
        int kk = w * 64 + nt * 16 + l15;
        float hb = Hb1[(size_t)h * 256 + kk];
        #pragma unroll
        for (int mt = 0; mt < 4; ++mt)
            #pragma unroll
            for (int r = 0; r < 4; ++r) {
                int c = mt * 16 + l4 * 4 + r;
                XT[c * MPAD + kk] = f2bf(gelu_exact(acc[mt][nt][r] + hb));
            }
    }
    __syncthreads();

    // ---- stage 3: out[c][p] = T @ HW2[h]^T + Hb2[h]; write transposed + residual ----
    const unsigned short* W3p = HW2b + (size_t)h * 65536;
    #pragma unroll
    for (int mt = 0; mt < 4; ++mt)
        #pragma unroll
        for (int nt = 0; nt < 4; ++nt) acc[mt][nt] = 0.f;
    for (int kc = 0; kc < 8; ++kc) {
        bf16x8 bfr[4];
        #pragma unroll
        for (int nt = 0; nt < 4; ++nt) {
            int p = w * 64 + nt * 16 + l15;
            bfr[nt] = *(const bf16x8*)(W3p + (size_t)p * 256 + kc * 32 + l4 * 8);
        }
        #pragma unroll
        for (int mt = 0; mt < 4; ++mt) {
            bf16x8 afr = *(const bf16x8*)&XT[(mt * 16 + l15) * MPAD + kc * 32 + l4 * 8];
            #pragma unroll
            for (int nt = 0; nt < 4; ++nt)
                acc[mt][nt] = __builtin_amdgcn_mfma_f32_16x16x32_bf16(afr, bfr[nt], acc[mt][nt], 0, 0, 0);
        }
    }
    #pragma unroll
    for (int nt = 0; nt < 4; ++nt) {
        int p = w * 64 + nt * 16 + l15;
        float hb = Hb2[(size_t)h * 256 + p];
        const float* xr = x + ((size_t)(b * 256 + p)) * 514 + h * 64;
        float* orow = out + ((size_t)(b * 256 + p)) * 514 + h * 64;
        #pragma unroll
        for (int mt = 0; mt < 4; ++mt) {
            int c0 = mt * 16 + l4 * 4;
            f32x2 x0 = *(const f32x2*)(xr + c0);
            f32x2 x1 = *(const f32x2*)(xr + c0 + 2);
            f32x2 o0, o1;
            o0.x = acc[mt][nt][0] + hb + x0.x;
            o0.y = acc[mt][nt][1] + hb + x0.y;
            o1.x = acc[mt][nt][2] + hb + x1.x;
            o1.y = acc[mt][nt][3] + hb + x1.y;
            *(f32x2*)(orow + c0) = o0;
            *(f32x2*)(orow + c0 + 2) = o1;
        }
    }
}

// ---------------------------------------------------------------------------
// fused FFN: one workgroup per 64 tokens. io rows (514 f32) -> bf16 LDS,
// loop 32 chunks of 64 dff: G = gelu(X@FW1c^T + b1) -> F += G@FW2c^T.
// Epilogue: io[:, :512] += F + Fb2 (in place, rows owned exclusively).
// ---------------------------------------------------------------------------
#define FXP 552  // 1104B row stride: 16B aligned, dw%32==20 (good banking)
#define FGP 72   // 144B row stride:  16B aligned, dw%32==4

__global__ __launch_bounds__(256, 2) void ffn_kernel(
    const unsigned short* __restrict__ FW1b,
    const unsigned short* __restrict__ FW2b,
    const float* __restrict__ Fb1, const float* __restrict__ Fb2,
    float* __restrict__ io) {
    __shared__ unsigned short XT[64 * FXP];
    __shared__ unsigned short G[64 * FGP];

    const size_t r0 = (size_t)blockIdx.x * 64;
    const int tid = threadIdx.x;
    const int lane = tid & 63;
    const int w = tid >> 6;
    const int l15 = lane & 15;
    const int l4 = lane >> 4;

    // stage tokens into LDS (bf16), zero pad K 514..551
    for (int i = tid; i < 64 * (FXP / 2); i += 256) {
        int row = i / (FXP / 2);
        int k = (i % (FXP / 2)) * 2;
        float v0 = 0.f, v1 = 0.f;
        if (k < 514) {
            const float* p = io + (r0 + row) * 514 + k;
            v0 = p[0];
            v1 = p[1];
        }
        *(unsigned int*)&XT[row * FXP + k] = pack2(v0, v1);
    }
    __syncthreads();

    f32x4 F[4][8];
    #pragma unroll
    for (int mt = 0; mt < 4; ++mt)
        #pragma unroll
        for (int nt = 0; nt < 8; ++nt) F[mt][nt] = 0.f;

    for (int dc = 0; dc < 32; ++dc) {
        // stage 1: this wave computes 16 dff columns: n = dc*64 + w*16 + l15
        f32x4 a1[4];
        #pragma unroll
        for (int mt = 0; mt < 4; ++mt) a1[mt] = 0.f;
        const int ndff = dc * 64 + w * 16 + l15;
        const unsigned short* brow = FW1b + (size_t)ndff * 544;
        for (int kc = 0; kc < 17; ++kc) {
            bf16x8 bf = *(const bf16x8*)(brow + kc * 32 + l4 * 8);
            #pragma unroll
            for (int mt = 0; mt < 4; ++mt) {
                bf16x8 af = *(const bf16x8*)&XT[(mt * 16 + l15) * FXP + kc * 32 + l4 * 8];
                a1[mt] = __builtin_amdgcn_mfma_f32_16x16x32_bf16(af, bf, a1[mt], 0, 0, 0);
            }
        }
        float b1 = Fb1[ndff];
        __syncthreads();  // previous chunk's G fully consumed
        #pragma unroll
        for (int mt = 0; mt < 4; ++mt)
            #pragma unroll
            for (int r = 0; r < 4; ++r) {
                int c = mt * 16 + l4 * 4 + r;
                G[c * FGP + w * 16 + l15] = f2bf(gelu_exact(a1[mt][r] + b1));
            }
        __syncthreads();
        // stage 2: F += G @ FW2chunk^T  (wave owns output cols w*128..w*128+127)
        #pragma unroll
        for (int kc2 = 0; kc2 < 2; ++kc2) {
            bf16x8 af2[4];
            #pragma unroll
            for (int mt = 0; mt < 4; ++mt)
                af2[mt] = *(const bf16x8*)&G[(mt * 16 + l15) * FGP + kc2 * 32 + l4 * 8];
            #pragma unroll
            for (int nt = 0; nt < 8; ++nt) {
                int n = w * 128 + nt * 16 + l15;
                bf16x8 bf2 = *(const bf16x8*)(FW2b + (size_t)n * 2048 + dc * 64 + kc2 * 32 + l4 * 8);
                #pragma unroll
                for (int mt = 0; mt < 4; ++mt)
                    F[mt][nt] = __builtin_amdgcn_mfma_f32_16x16x32_bf16(af2[mt], bf2, F[mt][nt], 0, 0, 0);
            }
        }
    }

    // epilogue: in-place residual add
    #pragma unroll
    for (int nt = 0; nt < 8; ++nt) {
        int col = w * 128 + nt * 16 + l15;
        float fb = Fb2[col];
        #pragma unroll
        for (int mt = 0; mt < 4; ++mt)
            #pragma unroll
            for (int r = 0; r < 4; ++r) {
                size_t row = r0 + mt * 16 + l4 * 4 + r;
                float* p = io + row * 514 + col;
                *p = F[mt][nt][r] + fb + *p;
            }
    }
}

// ---------------------------------------------------------------------------
extern "C" void kernel_launch(void* const* d_in, const int* in_sizes, int n_in,
                              void* d_out, int out_size, void* d_ws, size_t ws_size,
                              hipStream_t stream) {
    const float* x = (const float*)d_in[0];
    const float* Ws = (const float*)d_in[1];
    const float* bs = (const float*)d_in[2];
    const float* LW1 = (const float*)d_in[3];
    const float* Lb1 = (const float*)d_in[4];
    const float* LW2 = (const float*)d_in[5];
    const float* Lb2 = (const float*)d_in[6];
    const float* HW1 = (const float*)d_in[7];
    const float* Hb1 = (const float*)d_in[8];
    const float* HW2 = (const float*)d_in[9];
    const float* Hb2 = (const float*)d_in[10];
    const float* FW1 = (const float*)d_in[11];
    const float* Fb1 = (const float*)d_in[12];
    const float* FW2 = (const float*)d_in[13];
    const float* Fb2 = (const float*)d_in[14];
    float* out = (float*)d_out;

    char* ws = (char*)d_ws;
    unsigned short* Wsb = (unsigned short*)(ws);                 // 256*256
    unsigned short* HW1b = (unsigned short*)(ws + 131072);       // 8*256*256
    unsigned short* HW2b = (unsigned short*)(ws + 1179648);      // 8*256*256
    unsigned short* FW1b = (unsigned short*)(ws + 2228224);      // 2048*544 (padded)
    unsigned short* FW2b = (unsigned short*)(ws + 4456448);      // 512*2048
    float* gb = (float*)(ws + 6553600);                          // 256*512 f32

    cast_bf16_kernel<<<256, 256, 0, stream>>>(Ws, Wsb, 65536);
    cast_bf16_kernel<<<2048, 256, 0, stream>>>(HW1, HW1b, 524288);
    cast_bf16_kernel<<<2048, 256, 0, stream>>>(HW2, HW2b, 524288);
    cast_bf16_kernel<<<4096, 256, 0, stream>>>(FW2, FW2b, 1048576);
    cast_fw1_kernel<<<4352, 256, 0, stream>>>(FW1, FW1b);
    gb_kernel<<<256, 256, 0, stream>>>(x, LW1, Lb1, LW2, Lb2, gb);
    sc_copy_kernel<<<256, 256, 0, stream>>>(x, out);

    mixer_kernel<<<2048, 256, 0, stream>>>(x, bs, Hb1, Hb2, Wsb, HW1b, HW2b, gb, out);
    ffn_kernel<<<1024, 256, 0, stream>>>(FW1b, FW2b, Fb1, Fb2, out);
}